// Round 1
// baseline (20218.408 us; speedup 1.0000x reference)
//
#include <hip/hip_runtime.h>

#define N_USERS 100000
#define N_ITEMS 50000
#define N_TOTAL 150000
#define EMB 64
#define NNZ_CONST 8000000

// ---------------------------------------------------------------------------
// init: ego = concat(user_emb, item_emb); acc = ego   (float4 vectorized)
// ---------------------------------------------------------------------------
__global__ void lgcn_init_kernel(const float* __restrict__ user_emb,
                                 const float* __restrict__ item_emb,
                                 float* __restrict__ ego,
                                 float* __restrict__ acc) {
    const long total4 = (long)N_TOTAL * EMB / 4;   // 2.4M float4s
    long idx = (long)blockIdx.x * blockDim.x + threadIdx.x;
    if (idx >= total4) return;
    long e = idx * 4;
    const long user_elems = (long)N_USERS * EMB;
    float4 v;
    if (e < user_elems) {
        v = *(const float4*)(user_emb + e);
    } else {
        v = *(const float4*)(item_emb + (e - user_elems));
    }
    *(float4*)(ego + e) = v;
    *(float4*)(acc + e) = v;
}

// ---------------------------------------------------------------------------
// COO scatter SpMM: dst[rows[e], :] += vals[e] * src[cols[e], :]
// 16 threads cooperate on one edge; each thread handles 4 contiguous dims.
// ---------------------------------------------------------------------------
__global__ void lgcn_scatter_kernel(const int* __restrict__ rows,
                                    const int* __restrict__ cols,
                                    const float* __restrict__ vals,
                                    const float* __restrict__ src,
                                    float* __restrict__ dst) {
    const int lane16 = threadIdx.x & 15;
    const long tid = (long)blockIdx.x * blockDim.x + threadIdx.x;
    const long edge = tid >> 4;
    if (edge >= NNZ_CONST) return;

    const int r = rows[edge];
    const int c = cols[edge];
    const float v = vals[edge];

    const float4 x = *(const float4*)(src + (long)c * EMB + lane16 * 4);
    float* d = dst + (long)r * EMB + lane16 * 4;

    unsafeAtomicAdd(d + 0, v * x.x);
    unsafeAtomicAdd(d + 1, v * x.y);
    unsafeAtomicAdd(d + 2, v * x.z);
    unsafeAtomicAdd(d + 3, v * x.w);
}

// ---------------------------------------------------------------------------
// acc += layer_out  (and scale by 1/(L+1) on the final layer)
// ---------------------------------------------------------------------------
__global__ void lgcn_accum_kernel(float* __restrict__ acc,
                                  const float* __restrict__ layer_out,
                                  float scale) {
    const long total4 = (long)N_TOTAL * EMB / 4;
    long idx = (long)blockIdx.x * blockDim.x + threadIdx.x;
    if (idx >= total4) return;
    long e = idx * 4;
    float4 a = *(const float4*)(acc + e);
    float4 b = *(const float4*)(layer_out + e);
    a.x = (a.x + b.x) * scale;
    a.y = (a.y + b.y) * scale;
    a.z = (a.z + b.z) * scale;
    a.w = (a.w + b.w) * scale;
    *(float4*)(acc + e) = a;
}

extern "C" void kernel_launch(void* const* d_in, const int* in_sizes, int n_in,
                              void* d_out, int out_size, void* d_ws, size_t ws_size,
                              hipStream_t stream) {
    const float* user_emb = (const float*)d_in[0];
    const float* item_emb = (const float*)d_in[1];
    const int*   adj_rows = (const int*)d_in[2];
    const int*   adj_cols = (const int*)d_in[3];
    const float* adj_vals = (const float*)d_in[4];

    float* acc  = (float*)d_out;                    // N_TOTAL * EMB floats
    float* bufA = (float*)d_ws;                     // ego ping
    float* bufB = bufA + (size_t)N_TOTAL * EMB;     // ego pong

    const size_t ego_bytes = (size_t)N_TOTAL * EMB * sizeof(float);

    const int block = 256;
    const long total4 = (long)N_TOTAL * EMB / 4;
    const int grid_elem = (int)((total4 + block - 1) / block);

    // init: bufA = ego, acc = ego
    lgcn_init_kernel<<<grid_elem, block, 0, stream>>>(user_emb, item_emb, bufA, acc);

    const long scatter_threads = (long)NNZ_CONST * 16;
    const int grid_scatter = (int)((scatter_threads + block - 1) / block);

    float* src = bufA;
    float* dst = bufB;
    for (int layer = 0; layer < 3; ++layer) {
        hipMemsetAsync(dst, 0, ego_bytes, stream);
        lgcn_scatter_kernel<<<grid_scatter, block, 0, stream>>>(
            adj_rows, adj_cols, adj_vals, src, dst);
        const float scale = (layer == 2) ? 0.25f : 1.0f;
        lgcn_accum_kernel<<<grid_elem, block, 0, stream>>>(acc, dst, scale);
        float* t = src; src = dst; dst = t;
    }
}

// Round 2
// 2405.070 us; speedup vs baseline: 8.4066x; 8.4066x over previous
//
#include <hip/hip_runtime.h>

#define N_USERS 100000
#define N_ITEMS 50000
#define N_TOTAL 150000
#define EMB 64
#define NNZ_CONST 8000000

// ---------------------------------------------------------------------------
// init: ego = concat(user_emb, item_emb); acc = ego   (float4 vectorized)
// ---------------------------------------------------------------------------
__global__ void lgcn_init_kernel(const float* __restrict__ user_emb,
                                 const float* __restrict__ item_emb,
                                 float* __restrict__ ego,
                                 float* __restrict__ acc) {
    const long total4 = (long)N_TOTAL * EMB / 4;
    long idx = (long)blockIdx.x * blockDim.x + threadIdx.x;
    if (idx >= total4) return;
    long e = idx * 4;
    const long user_elems = (long)N_USERS * EMB;
    float4 v;
    if (e < user_elems) {
        v = *(const float4*)(user_emb + e);
    } else {
        v = *(const float4*)(item_emb + (e - user_elems));
    }
    *(float4*)(ego + e) = v;
    *(float4*)(acc + e) = v;
}

// ---------------------------------------------------------------------------
// CSR build step 1: histogram of row indices (int atomics, L2-combined)
// ---------------------------------------------------------------------------
__global__ void lgcn_hist_kernel(const int* __restrict__ rows,
                                 int* __restrict__ counts) {
    long e = (long)blockIdx.x * blockDim.x + threadIdx.x;
    if (e >= NNZ_CONST) return;
    atomicAdd(&counts[rows[e]], 1);
}

// ---------------------------------------------------------------------------
// CSR build step 2: exclusive scan of 150K counts. Single block, 1024 threads,
// each owns a contiguous chunk; LDS Hillis-Steele across thread sums.
// Writes row_ptr[0..N] and cursor[0..N-1] (fill cursors).
// ---------------------------------------------------------------------------
__global__ void lgcn_scan_kernel(const int* __restrict__ counts,
                                 int* __restrict__ row_ptr,
                                 int* __restrict__ cursor) {
    __shared__ int lds[1024];
    const int t = threadIdx.x;
    const int CHUNK = (N_TOTAL + 1023) / 1024;   // 147
    const int begin = t * CHUNK;
    const int endi = min(begin + CHUNK, N_TOTAL);
    int local = 0;
    for (int i = begin; i < endi; ++i) local += counts[i];
    lds[t] = local;
    __syncthreads();
    for (int off = 1; off < 1024; off <<= 1) {
        int v = (t >= off) ? lds[t - off] : 0;
        __syncthreads();
        lds[t] += v;
        __syncthreads();
    }
    int run = lds[t] - local;   // exclusive prefix of this thread's chunk
    for (int i = begin; i < endi; ++i) {
        int c = counts[i];
        row_ptr[i] = run;
        cursor[i]  = run;
        run += c;
    }
    if (t == 1023) row_ptr[N_TOTAL] = run;   // total
}

// ---------------------------------------------------------------------------
// CSR build step 3: scatter edges into sorted order
// ---------------------------------------------------------------------------
__global__ void lgcn_fill_kernel(const int* __restrict__ rows,
                                 const int* __restrict__ cols,
                                 const float* __restrict__ vals,
                                 int* __restrict__ cursor,
                                 int* __restrict__ col_sorted,
                                 float* __restrict__ val_sorted) {
    long e = (long)blockIdx.x * blockDim.x + threadIdx.x;
    if (e >= NNZ_CONST) return;
    int r = rows[e];
    int pos = atomicAdd(&cursor[r], 1);
    col_sorted[pos] = cols[e];
    val_sorted[pos] = vals[e];
}

// ---------------------------------------------------------------------------
// Gather SpMM + fused accumulate: one wave per row, lane = dim.
// dst[row,:] = sum_e val[e]*src[col[e],:]; acc[row,:] = (acc+dst)*scale
// ---------------------------------------------------------------------------
__global__ void lgcn_spmm_kernel(const int* __restrict__ row_ptr,
                                 const int* __restrict__ cols,
                                 const float* __restrict__ vals,
                                 const float* __restrict__ src,
                                 float* __restrict__ dst,
                                 float* __restrict__ acc,
                                 float scale) {
    const int wave = threadIdx.x >> 6;
    const int lane = threadIdx.x & 63;
    const int row = blockIdx.x * 4 + wave;
    if (row >= N_TOTAL) return;
    const int start = row_ptr[row];
    const int end   = row_ptr[row + 1];
    float s0 = 0.f, s1 = 0.f;
    int e = start;
    for (; e + 2 <= end; e += 2) {
        const int   c0 = cols[e];
        const int   c1 = cols[e + 1];
        const float v0 = vals[e];
        const float v1 = vals[e + 1];
        s0 += v0 * src[(size_t)c0 * EMB + lane];
        s1 += v1 * src[(size_t)c1 * EMB + lane];
    }
    if (e < end) {
        s0 += vals[e] * src[(size_t)cols[e] * EMB + lane];
    }
    const float s = s0 + s1;
    const size_t o = (size_t)row * EMB + lane;
    dst[o] = s;
    acc[o] = (acc[o] + s) * scale;
}

extern "C" void kernel_launch(void* const* d_in, const int* in_sizes, int n_in,
                              void* d_out, int out_size, void* d_ws, size_t ws_size,
                              hipStream_t stream) {
    const float* user_emb = (const float*)d_in[0];
    const float* item_emb = (const float*)d_in[1];
    const int*   adj_rows = (const int*)d_in[2];
    const int*   adj_cols = (const int*)d_in[3];
    const float* adj_vals = (const float*)d_in[4];

    float* acc  = (float*)d_out;                       // N_TOTAL*EMB

    // workspace layout
    char* ws = (char*)d_ws;
    float* bufA       = (float*)ws;                          ws += (size_t)N_TOTAL * EMB * 4;
    float* bufB       = (float*)ws;                          ws += (size_t)N_TOTAL * EMB * 4;
    int*   row_ptr    = (int*)ws;                            ws += (size_t)(N_TOTAL + 1) * 4;
    int*   cursor     = (int*)ws;                            ws += (size_t)N_TOTAL * 4;
    int*   col_sorted = (int*)ws;                            ws += (size_t)NNZ_CONST * 4;
    float* val_sorted = (float*)ws;                          ws += (size_t)NNZ_CONST * 4;

    const int block = 256;
    const long total4 = (long)N_TOTAL * EMB / 4;
    const int grid_elem = (int)((total4 + block - 1) / block);
    const int grid_edge = (NNZ_CONST + block - 1) / block;

    // init ego + acc
    lgcn_init_kernel<<<grid_elem, block, 0, stream>>>(user_emb, item_emb, bufA, acc);

    // ---- build CSR ----
    hipMemsetAsync(cursor, 0, (size_t)N_TOTAL * 4, stream);  // counts
    lgcn_hist_kernel<<<grid_edge, block, 0, stream>>>(adj_rows, cursor);
    lgcn_scan_kernel<<<1, 1024, 0, stream>>>(cursor, row_ptr, cursor);
    lgcn_fill_kernel<<<grid_edge, block, 0, stream>>>(adj_rows, adj_cols, adj_vals,
                                                      cursor, col_sorted, val_sorted);

    // ---- 3 propagation layers, gather-SpMM, fused accumulate ----
    const int grid_spmm = (N_TOTAL + 3) / 4;   // 4 rows (waves) per block
    float* src = bufA;
    float* dst = bufB;
    for (int layer = 0; layer < 3; ++layer) {
        const float scale = (layer == 2) ? 0.25f : 1.0f;
        lgcn_spmm_kernel<<<grid_spmm, block, 0, stream>>>(
            row_ptr, col_sorted, val_sorted, src, dst, acc, scale);
        float* t = src; src = dst; dst = t;
    }
}

// Round 4
// 2166.811 us; speedup vs baseline: 9.3309x; 1.1100x over previous
//
#include <hip/hip_runtime.h>

#define N_USERS 100000
#define N_ITEMS 50000
#define N_TOTAL 150000
#define EMB 64
#define NNZ_CONST 8000000

// ---------------------------------------------------------------------------
// init: ego = concat(user_emb, item_emb); acc = ego   (float4 vectorized)
// ---------------------------------------------------------------------------
__global__ void lgcn_init_kernel(const float* __restrict__ user_emb,
                                 const float* __restrict__ item_emb,
                                 float* __restrict__ ego,
                                 float* __restrict__ acc) {
    const long total4 = (long)N_TOTAL * EMB / 4;
    long idx = (long)blockIdx.x * blockDim.x + threadIdx.x;
    if (idx >= total4) return;
    long e = idx * 4;
    const long user_elems = (long)N_USERS * EMB;
    float4 v;
    if (e < user_elems) {
        v = *(const float4*)(user_emb + e);
    } else {
        v = *(const float4*)(item_emb + (e - user_elems));
    }
    *(float4*)(ego + e) = v;
    *(float4*)(acc + e) = v;
}

// ---------------------------------------------------------------------------
// CSR build step 1: histogram of row indices (int4-vectorized reads)
// ---------------------------------------------------------------------------
__global__ void lgcn_hist_kernel(const int* __restrict__ rows,
                                 int* __restrict__ counts) {
    long t = (long)blockIdx.x * blockDim.x + threadIdx.x;
    long e4 = t * 4;
    if (e4 >= NNZ_CONST) return;
    int4 r = *(const int4*)(rows + e4);
    atomicAdd(&counts[r.x], 1);
    atomicAdd(&counts[r.y], 1);
    atomicAdd(&counts[r.z], 1);
    atomicAdd(&counts[r.w], 1);
}

// ---------------------------------------------------------------------------
// CSR build step 2: exclusive scan of 150K counts. Single block, 1024 threads.
// ---------------------------------------------------------------------------
__global__ void lgcn_scan_kernel(const int* __restrict__ counts,
                                 int* __restrict__ row_ptr,
                                 int* __restrict__ cursor) {
    __shared__ int lds[1024];
    const int t = threadIdx.x;
    const int CHUNK = (N_TOTAL + 1023) / 1024;   // 147
    const int begin = t * CHUNK;
    const int endi = min(begin + CHUNK, N_TOTAL);
    int local = 0;
    for (int i = begin; i < endi; ++i) local += counts[i];
    lds[t] = local;
    __syncthreads();
    for (int off = 1; off < 1024; off <<= 1) {
        int v = (t >= off) ? lds[t - off] : 0;
        __syncthreads();
        lds[t] += v;
        __syncthreads();
    }
    int run = lds[t] - local;   // exclusive prefix of this thread's chunk
    for (int i = begin; i < endi; ++i) {
        int c = counts[i];
        row_ptr[i] = run;
        cursor[i]  = run;
        run += c;
    }
    if (t == 1023) row_ptr[N_TOTAL] = run;
}

// ---------------------------------------------------------------------------
// CSR build step 3: scatter (col,val) PAIRS into sorted order.
// One 8B nontemporal store per edge, packed as u64 (col=low32, val=high32,
// little-endian => matches float2{x=col_bits, y=val} on load).
// ---------------------------------------------------------------------------
__global__ void lgcn_fill_kernel(const int* __restrict__ rows,
                                 const int* __restrict__ cols,
                                 const float* __restrict__ vals,
                                 int* __restrict__ cursor,
                                 unsigned long long* __restrict__ pairs) {
    long e = (long)blockIdx.x * blockDim.x + threadIdx.x;
    if (e >= NNZ_CONST) return;
    int r = rows[e];
    int pos = atomicAdd(&cursor[r], 1);
    unsigned long long packed =
        ((unsigned long long)__float_as_uint(vals[e]) << 32) |
        (unsigned int)cols[e];
    __builtin_nontemporal_store(packed, &pairs[pos]);
}

// ---------------------------------------------------------------------------
// Gather SpMM + fused accumulate.
// One wave per row; 4x 16-lane groups each process a different edge with
// float4 loads (4 edges in flight). Cross-group __shfl_xor reduce at end.
// ---------------------------------------------------------------------------
__global__ void lgcn_spmm_kernel(const int* __restrict__ row_ptr,
                                 const unsigned long long* __restrict__ pairs,
                                 const float* __restrict__ src,
                                 float* __restrict__ dst,
                                 float* __restrict__ acc,
                                 float scale) {
    const int wave = threadIdx.x >> 6;
    const int lane = threadIdx.x & 63;
    const int grp  = lane >> 4;     // 0..3 : which edge in the 4-batch
    const int l16  = lane & 15;     // dim group: handles dims [l16*4, l16*4+4)
    const int row = blockIdx.x * 4 + wave;
    if (row >= N_TOTAL) return;
    const int start = row_ptr[row];
    const int end   = row_ptr[row + 1];

    float4 s = make_float4(0.f, 0.f, 0.f, 0.f);
    for (int e = start + grp; e < end; e += 4) {
        const unsigned long long p = pairs[e];
        const int   c = (int)(unsigned int)(p & 0xFFFFFFFFull);
        const float v = __uint_as_float((unsigned int)(p >> 32));
        const float4 x = *(const float4*)(src + (size_t)c * EMB + l16 * 4);
        s.x += v * x.x;
        s.y += v * x.y;
        s.z += v * x.z;
        s.w += v * x.w;
    }
    // reduce the 4 edge-groups (lanes sharing l16) down to group 0
    s.x += __shfl_xor(s.x, 16); s.y += __shfl_xor(s.y, 16);
    s.z += __shfl_xor(s.z, 16); s.w += __shfl_xor(s.w, 16);
    s.x += __shfl_xor(s.x, 32); s.y += __shfl_xor(s.y, 32);
    s.z += __shfl_xor(s.z, 32); s.w += __shfl_xor(s.w, 32);

    if (grp == 0) {
        const size_t o = (size_t)row * EMB + l16 * 4;
        *(float4*)(dst + o) = s;
        float4 a = *(const float4*)(acc + o);
        a.x = (a.x + s.x) * scale;
        a.y = (a.y + s.y) * scale;
        a.z = (a.z + s.z) * scale;
        a.w = (a.w + s.w) * scale;
        *(float4*)(acc + o) = a;
    }
}

extern "C" void kernel_launch(void* const* d_in, const int* in_sizes, int n_in,
                              void* d_out, int out_size, void* d_ws, size_t ws_size,
                              hipStream_t stream) {
    const float* user_emb = (const float*)d_in[0];
    const float* item_emb = (const float*)d_in[1];
    const int*   adj_rows = (const int*)d_in[2];
    const int*   adj_cols = (const int*)d_in[3];
    const float* adj_vals = (const float*)d_in[4];

    float* acc = (float*)d_out;

    // workspace layout
    char* ws = (char*)d_ws;
    float* bufA    = (float*)ws;                ws += (size_t)N_TOTAL * EMB * 4;   // 38.4 MB
    float* bufB    = (float*)ws;                ws += (size_t)N_TOTAL * EMB * 4;   // 38.4 MB
    unsigned long long* pairs = (unsigned long long*)ws;
                                                ws += (size_t)NNZ_CONST * 8;       // 64 MB
    int*   row_ptr = (int*)ws;                  ws += (size_t)(N_TOTAL + 2) * 4;
    int*   cursor  = (int*)ws;                  ws += (size_t)N_TOTAL * 4;

    const int block = 256;
    const long total4 = (long)N_TOTAL * EMB / 4;
    const int grid_elem = (int)((total4 + block - 1) / block);

    // init ego + acc
    lgcn_init_kernel<<<grid_elem, block, 0, stream>>>(user_emb, item_emb, bufA, acc);

    // ---- build CSR (pairs form) ----
    (void)hipMemsetAsync(cursor, 0, (size_t)N_TOTAL * 4, stream);
    const int grid_hist = (NNZ_CONST / 4 + block - 1) / block;
    lgcn_hist_kernel<<<grid_hist, block, 0, stream>>>(adj_rows, cursor);
    lgcn_scan_kernel<<<1, 1024, 0, stream>>>(cursor, row_ptr, cursor);
    const int grid_edge = (NNZ_CONST + block - 1) / block;
    lgcn_fill_kernel<<<grid_edge, block, 0, stream>>>(adj_rows, adj_cols, adj_vals,
                                                      cursor, pairs);

    // ---- 3 propagation layers ----
    const int grid_spmm = (N_TOTAL + 3) / 4;
    float* src = bufA;
    float* dst = bufB;
    for (int layer = 0; layer < 3; ++layer) {
        const float scale = (layer == 2) ? 0.25f : 1.0f;
        lgcn_spmm_kernel<<<grid_spmm, block, 0, stream>>>(
            row_ptr, pairs, src, dst, acc, scale);
        float* t = src; src = dst; dst = t;
    }
}

// Round 5
// 2126.005 us; speedup vs baseline: 9.5100x; 1.0192x over previous
//
#include <hip/hip_runtime.h>

#define N_USERS 100000
#define N_ITEMS 50000
#define N_TOTAL 150000
#define EMB 64
#define NNZ_CONST 8000000

typedef unsigned short u16;
typedef unsigned int u32;
typedef unsigned long long u64;

// f32 -> bf16 with round-to-nearest-even
__device__ __forceinline__ u16 f32_to_bf16(float f) {
    u32 b = __float_as_uint(f);
    b += 0x7FFFu + ((b >> 16) & 1u);
    return (u16)(b >> 16);
}
__device__ __forceinline__ float bf16_to_f32(u16 h) {
    return __uint_as_float((u32)h << 16);
}

// ---------------------------------------------------------------------------
// init: acc = concat(user,item) (f32);  ego0 = bf16 mirror
// ---------------------------------------------------------------------------
__global__ void lgcn_init_kernel(const float* __restrict__ user_emb,
                                 const float* __restrict__ item_emb,
                                 float* __restrict__ acc,
                                 u16* __restrict__ ego_bf16) {
    const long total4 = (long)N_TOTAL * EMB / 4;
    long idx = (long)blockIdx.x * blockDim.x + threadIdx.x;
    if (idx >= total4) return;
    long e = idx * 4;
    const long user_elems = (long)N_USERS * EMB;
    float4 v;
    if (e < user_elems) {
        v = *(const float4*)(user_emb + e);
    } else {
        v = *(const float4*)(item_emb + (e - user_elems));
    }
    *(float4*)(acc + e) = v;
    ushort4 h;
    h.x = f32_to_bf16(v.x);
    h.y = f32_to_bf16(v.y);
    h.z = f32_to_bf16(v.z);
    h.w = f32_to_bf16(v.w);
    *(ushort4*)(ego_bf16 + e) = h;
}

// ---------------------------------------------------------------------------
// CSR build step 1: histogram of row indices (int4-vectorized reads)
// ---------------------------------------------------------------------------
__global__ void lgcn_hist_kernel(const int* __restrict__ rows,
                                 int* __restrict__ counts) {
    long t = (long)blockIdx.x * blockDim.x + threadIdx.x;
    long e4 = t * 4;
    if (e4 >= NNZ_CONST) return;
    int4 r = *(const int4*)(rows + e4);
    atomicAdd(&counts[r.x], 1);
    atomicAdd(&counts[r.y], 1);
    atomicAdd(&counts[r.z], 1);
    atomicAdd(&counts[r.w], 1);
}

// ---------------------------------------------------------------------------
// CSR build step 2: exclusive scan of 150K counts. Single block, 1024 threads.
// ---------------------------------------------------------------------------
__global__ void lgcn_scan_kernel(const int* __restrict__ counts,
                                 int* __restrict__ row_ptr,
                                 int* __restrict__ cursor) {
    __shared__ int lds[1024];
    const int t = threadIdx.x;
    const int CHUNK = (N_TOTAL + 1023) / 1024;   // 147
    const int begin = t * CHUNK;
    const int endi = min(begin + CHUNK, N_TOTAL);
    int local = 0;
    for (int i = begin; i < endi; ++i) local += counts[i];
    lds[t] = local;
    __syncthreads();
    for (int off = 1; off < 1024; off <<= 1) {
        int v = (t >= off) ? lds[t - off] : 0;
        __syncthreads();
        lds[t] += v;
        __syncthreads();
    }
    int run = lds[t] - local;   // exclusive prefix of this thread's chunk
    for (int i = begin; i < endi; ++i) {
        int c = counts[i];
        row_ptr[i] = run;
        cursor[i]  = run;
        run += c;
    }
    if (t == 1023) row_ptr[N_TOTAL] = run;
}

// ---------------------------------------------------------------------------
// CSR build step 3: scatter (col,val) pairs into row-sorted order.
// One plain 8B store per edge — L2 assembles full lines (NT store regressed).
// ---------------------------------------------------------------------------
__global__ void lgcn_fill_kernel(const int* __restrict__ rows,
                                 const int* __restrict__ cols,
                                 const float* __restrict__ vals,
                                 int* __restrict__ cursor,
                                 u64* __restrict__ pairs) {
    long e = (long)blockIdx.x * blockDim.x + threadIdx.x;
    if (e >= NNZ_CONST) return;
    int r = rows[e];
    int pos = atomicAdd(&cursor[r], 1);
    u64 packed = ((u64)__float_as_uint(vals[e]) << 32) | (u32)cols[e];
    pairs[pos] = packed;
}

// ---------------------------------------------------------------------------
// Gather SpMM (bf16 src) + fused f32 accumulate, bf16 dst for next layer.
// One wave per row; 4x 16-lane groups each process a different edge
// (4 edges in flight). Cross-group __shfl_xor reduce at end.
// ---------------------------------------------------------------------------
__global__ void lgcn_spmm_kernel(const int* __restrict__ row_ptr,
                                 const u64* __restrict__ pairs,
                                 const u16* __restrict__ src,
                                 u16* __restrict__ dst,
                                 float* __restrict__ acc,
                                 float scale) {
    const int wave = threadIdx.x >> 6;
    const int lane = threadIdx.x & 63;
    const int grp  = lane >> 4;     // 0..3 : which edge of the 4-batch
    const int l16  = lane & 15;     // dims [l16*4, l16*4+4)
    const int row = blockIdx.x * 4 + wave;
    if (row >= N_TOTAL) return;
    const int start = row_ptr[row];
    const int end   = row_ptr[row + 1];

    float4 s = make_float4(0.f, 0.f, 0.f, 0.f);
    for (int e = start + grp; e < end; e += 4) {
        const u64 p = __builtin_nontemporal_load(&pairs[e]);
        const int   c = (int)(u32)(p & 0xFFFFFFFFull);
        const float v = __uint_as_float((u32)(p >> 32));
        const ushort4 xb = *(const ushort4*)(src + (size_t)c * EMB + l16 * 4);
        s.x += v * bf16_to_f32(xb.x);
        s.y += v * bf16_to_f32(xb.y);
        s.z += v * bf16_to_f32(xb.z);
        s.w += v * bf16_to_f32(xb.w);
    }
    // reduce the 4 edge-groups (lanes sharing l16) down to group 0
    s.x += __shfl_xor(s.x, 16); s.y += __shfl_xor(s.y, 16);
    s.z += __shfl_xor(s.z, 16); s.w += __shfl_xor(s.w, 16);
    s.x += __shfl_xor(s.x, 32); s.y += __shfl_xor(s.y, 32);
    s.z += __shfl_xor(s.z, 32); s.w += __shfl_xor(s.w, 32);

    if (grp == 0) {
        const size_t o = (size_t)row * EMB + l16 * 4;
        ushort4 h;
        h.x = f32_to_bf16(s.x);
        h.y = f32_to_bf16(s.y);
        h.z = f32_to_bf16(s.z);
        h.w = f32_to_bf16(s.w);
        *(ushort4*)(dst + o) = h;
        float4 a = *(const float4*)(acc + o);
        a.x = (a.x + s.x) * scale;
        a.y = (a.y + s.y) * scale;
        a.z = (a.z + s.z) * scale;
        a.w = (a.w + s.w) * scale;
        *(float4*)(acc + o) = a;
    }
}

extern "C" void kernel_launch(void* const* d_in, const int* in_sizes, int n_in,
                              void* d_out, int out_size, void* d_ws, size_t ws_size,
                              hipStream_t stream) {
    const float* user_emb = (const float*)d_in[0];
    const float* item_emb = (const float*)d_in[1];
    const int*   adj_rows = (const int*)d_in[2];
    const int*   adj_cols = (const int*)d_in[3];
    const float* adj_vals = (const float*)d_in[4];

    float* acc = (float*)d_out;

    // workspace layout
    char* ws = (char*)d_ws;
    u16* egoA = (u16*)ws;           ws += (size_t)N_TOTAL * EMB * 2;   // 19.2 MB
    u16* egoB = (u16*)ws;           ws += (size_t)N_TOTAL * EMB * 2;   // 19.2 MB
    u64* pairs = (u64*)ws;          ws += (size_t)NNZ_CONST * 8;       // 64 MB
    int* row_ptr = (int*)ws;        ws += (size_t)(N_TOTAL + 2) * 4;
    int* cursor  = (int*)ws;        ws += (size_t)N_TOTAL * 4;

    const int block = 256;
    const long total4 = (long)N_TOTAL * EMB / 4;
    const int grid_elem = (int)((total4 + block - 1) / block);

    // init acc (f32) + ego0 (bf16)
    lgcn_init_kernel<<<grid_elem, block, 0, stream>>>(user_emb, item_emb, acc, egoA);

    // ---- build CSR (pairs form) ----
    (void)hipMemsetAsync(cursor, 0, (size_t)N_TOTAL * 4, stream);
    const int grid_hist = (NNZ_CONST / 4 + block - 1) / block;
    lgcn_hist_kernel<<<grid_hist, block, 0, stream>>>(adj_rows, cursor);
    lgcn_scan_kernel<<<1, 1024, 0, stream>>>(cursor, row_ptr, cursor);
    const int grid_edge = (NNZ_CONST + block - 1) / block;
    lgcn_fill_kernel<<<grid_edge, block, 0, stream>>>(adj_rows, adj_cols, adj_vals,
                                                      cursor, pairs);

    // ---- 3 propagation layers ----
    const int grid_spmm = (N_TOTAL + 3) / 4;
    u16* src = egoA;
    u16* dst = egoB;
    for (int layer = 0; layer < 3; ++layer) {
        const float scale = (layer == 2) ? 0.25f : 1.0f;
        lgcn_spmm_kernel<<<grid_spmm, block, 0, stream>>>(
            row_ptr, pairs, src, dst, acc, scale);
        u16* t = src; src = dst; dst = t;
    }
}

// Round 6
// 1420.923 us; speedup vs baseline: 14.2291x; 1.4962x over previous
//
#include <hip/hip_runtime.h>

#define N_USERS 100000
#define N_ITEMS 50000
#define N_TOTAL 150000
#define EMB 64
#define NNZ_CONST 8000000

typedef unsigned short u16;
typedef unsigned int u32;
typedef unsigned long long u64;

// f32 -> bf16 with round-to-nearest-even
__device__ __forceinline__ u16 f32_to_bf16(float f) {
    u32 b = __float_as_uint(f);
    b += 0x7FFFu + ((b >> 16) & 1u);
    return (u16)(b >> 16);
}
__device__ __forceinline__ float bf16lo_to_f32(u32 w) {   // low 16 bits
    return __uint_as_float(w << 16);
}
__device__ __forceinline__ float bf16hi_to_f32(u32 w) {   // high 16 bits
    return __uint_as_float(w & 0xFFFF0000u);
}

// ---------------------------------------------------------------------------
// init: acc = concat(user,item) (f32);  ego0 = bf16 mirror
// ---------------------------------------------------------------------------
__global__ void lgcn_init_kernel(const float* __restrict__ user_emb,
                                 const float* __restrict__ item_emb,
                                 float* __restrict__ acc,
                                 u16* __restrict__ ego_bf16) {
    const long total4 = (long)N_TOTAL * EMB / 4;
    long idx = (long)blockIdx.x * blockDim.x + threadIdx.x;
    if (idx >= total4) return;
    long e = idx * 4;
    const long user_elems = (long)N_USERS * EMB;
    float4 v;
    if (e < user_elems) {
        v = *(const float4*)(user_emb + e);
    } else {
        v = *(const float4*)(item_emb + (e - user_elems));
    }
    *(float4*)(acc + e) = v;
    ushort4 h;
    h.x = f32_to_bf16(v.x);
    h.y = f32_to_bf16(v.y);
    h.z = f32_to_bf16(v.z);
    h.w = f32_to_bf16(v.w);
    *(ushort4*)(ego_bf16 + e) = h;
}

// ---------------------------------------------------------------------------
// CSR build step 1: histogram of row indices (int4-vectorized reads)
// ---------------------------------------------------------------------------
__global__ void lgcn_hist_kernel(const int* __restrict__ rows,
                                 int* __restrict__ counts) {
    long t = (long)blockIdx.x * blockDim.x + threadIdx.x;
    long e4 = t * 4;
    if (e4 >= NNZ_CONST) return;
    int4 r = *(const int4*)(rows + e4);
    atomicAdd(&counts[r.x], 1);
    atomicAdd(&counts[r.y], 1);
    atomicAdd(&counts[r.z], 1);
    atomicAdd(&counts[r.w], 1);
}

// ---------------------------------------------------------------------------
// CSR build step 2a: per-block reduce (1024 counts per block of 256 threads)
// ---------------------------------------------------------------------------
#define SCAN_ITEMS 1024
#define SCAN_BLOCKS ((N_TOTAL + SCAN_ITEMS - 1) / SCAN_ITEMS)   // 147

__global__ void lgcn_scan_reduce_kernel(const int* __restrict__ counts,
                                        int* __restrict__ partials) {
    __shared__ int lds[256];
    const int b = blockIdx.x, t = threadIdx.x;
    long idx = (long)b * SCAN_ITEMS + t * 4;
    int sum = 0;
    if (idx + 4 <= N_TOTAL) {
        int4 c = *(const int4*)(counts + idx);
        sum = c.x + c.y + c.z + c.w;
    } else {
        for (int i = 0; i < 4; ++i)
            if (idx + i < N_TOTAL) sum += counts[idx + i];
    }
    lds[t] = sum;
    __syncthreads();
    for (int off = 128; off; off >>= 1) {
        if (t < off) lds[t] += lds[t + off];
        __syncthreads();
    }
    if (t == 0) partials[b] = lds[0];
}

// ---------------------------------------------------------------------------
// CSR build step 2b: single-block exclusive scan of 147 partials
// ---------------------------------------------------------------------------
__global__ void lgcn_scan_partials_kernel(int* __restrict__ partials,
                                          int* __restrict__ total_out) {
    __shared__ int lds[256];
    const int t = threadIdx.x;
    int v = (t < SCAN_BLOCKS) ? partials[t] : 0;
    lds[t] = v;
    __syncthreads();
    for (int off = 1; off < 256; off <<= 1) {
        int u = (t >= off) ? lds[t - off] : 0;
        __syncthreads();
        lds[t] += u;
        __syncthreads();
    }
    if (t < SCAN_BLOCKS) partials[t] = lds[t] - v;   // exclusive
    if (t == SCAN_BLOCKS - 1) *total_out = lds[t];   // = NNZ -> row_ptr[N_TOTAL]
}

// ---------------------------------------------------------------------------
// CSR build step 2c: apply — block-local scan + partial offset, write
// row_ptr[0..N) and cursor[0..N)
// ---------------------------------------------------------------------------
__global__ void lgcn_scan_apply_kernel(const int* __restrict__ counts,
                                       const int* __restrict__ partials,
                                       int* __restrict__ row_ptr,
                                       int* __restrict__ cursor) {
    __shared__ int lds[256];
    const int b = blockIdx.x, t = threadIdx.x;
    long idx = (long)b * SCAN_ITEMS + t * 4;
    int4 c = make_int4(0, 0, 0, 0);
    if (idx + 4 <= N_TOTAL) {
        c = *(const int4*)(counts + idx);
    } else {
        if (idx + 0 < N_TOTAL) c.x = counts[idx + 0];
        if (idx + 1 < N_TOTAL) c.y = counts[idx + 1];
        if (idx + 2 < N_TOTAL) c.z = counts[idx + 2];
        if (idx + 3 < N_TOTAL) c.w = counts[idx + 3];
    }
    const int tsum = c.x + c.y + c.z + c.w;
    lds[t] = tsum;
    __syncthreads();
    for (int off = 1; off < 256; off <<= 1) {
        int u = (t >= off) ? lds[t - off] : 0;
        __syncthreads();
        lds[t] += u;
        __syncthreads();
    }
    int run = lds[t] - tsum + partials[b];   // exclusive prefix for this thread
    int4 r;
    r.x = run;
    r.y = r.x + c.x;
    r.z = r.y + c.y;
    r.w = r.z + c.z;
    if (idx + 4 <= N_TOTAL) {
        *(int4*)(row_ptr + idx) = r;
        *(int4*)(cursor + idx) = r;
    } else {
        if (idx + 0 < N_TOTAL) { row_ptr[idx + 0] = r.x; cursor[idx + 0] = r.x; }
        if (idx + 1 < N_TOTAL) { row_ptr[idx + 1] = r.y; cursor[idx + 1] = r.y; }
        if (idx + 2 < N_TOTAL) { row_ptr[idx + 2] = r.z; cursor[idx + 2] = r.z; }
        if (idx + 3 < N_TOTAL) { row_ptr[idx + 3] = r.w; cursor[idx + 3] = r.w; }
    }
}

// ---------------------------------------------------------------------------
// CSR build step 3: scatter (col,val) pairs into row-sorted order.
// ---------------------------------------------------------------------------
__global__ void lgcn_fill_kernel(const int* __restrict__ rows,
                                 const int* __restrict__ cols,
                                 const float* __restrict__ vals,
                                 int* __restrict__ cursor,
                                 u64* __restrict__ pairs) {
    long e = (long)blockIdx.x * blockDim.x + threadIdx.x;
    if (e >= NNZ_CONST) return;
    int r = rows[e];
    int pos = atomicAdd(&cursor[r], 1);
    u64 packed = ((u64)__float_as_uint(vals[e]) << 32) | (u32)cols[e];
    pairs[pos] = packed;
}

// ---------------------------------------------------------------------------
// Gather SpMM (bf16 src) + fused f32 accumulate, bf16 dst for next layer.
// One wave per row; 8 groups x 8 lanes. Each lane loads 8 bf16 dims (16B).
// Hand-unrolled x2 => 16 edges in flight per wave. Cross-group shfl reduce.
// ---------------------------------------------------------------------------
__global__ void lgcn_spmm_kernel(const int* __restrict__ row_ptr,
                                 const u64* __restrict__ pairs,
                                 const u16* __restrict__ src,
                                 u16* __restrict__ dst,
                                 float* __restrict__ acc,
                                 float scale) {
    const int wave = threadIdx.x >> 6;
    const int lane = threadIdx.x & 63;
    const int grp  = lane >> 3;     // 0..7 : edge slot within 8-batch
    const int l8   = lane & 7;      // dims [l8*8, l8*8+8)
    const int row = blockIdx.x * 4 + wave;
    if (row >= N_TOTAL) return;
    const int start = row_ptr[row];
    const int end   = row_ptr[row + 1];

    float4 a0 = make_float4(0.f, 0.f, 0.f, 0.f);
    float4 a1 = make_float4(0.f, 0.f, 0.f, 0.f);
    float4 b0 = make_float4(0.f, 0.f, 0.f, 0.f);
    float4 b1 = make_float4(0.f, 0.f, 0.f, 0.f);

    int e = start + grp;
    for (; e + 8 < end; e += 16) {
        const u64 p0 = __builtin_nontemporal_load(&pairs[e]);
        const u64 p1 = __builtin_nontemporal_load(&pairs[e + 8]);
        const int   c0 = (int)(u32)(p0 & 0xFFFFFFFFull);
        const float v0 = __uint_as_float((u32)(p0 >> 32));
        const int   c1 = (int)(u32)(p1 & 0xFFFFFFFFull);
        const float v1 = __uint_as_float((u32)(p1 >> 32));
        const uint4 x0 = *(const uint4*)(src + (size_t)c0 * EMB + l8 * 8);
        const uint4 x1 = *(const uint4*)(src + (size_t)c1 * EMB + l8 * 8);
        a0.x += v0 * bf16lo_to_f32(x0.x);  a0.y += v0 * bf16hi_to_f32(x0.x);
        a0.z += v0 * bf16lo_to_f32(x0.y);  a0.w += v0 * bf16hi_to_f32(x0.y);
        a1.x += v0 * bf16lo_to_f32(x0.z);  a1.y += v0 * bf16hi_to_f32(x0.z);
        a1.z += v0 * bf16lo_to_f32(x0.w);  a1.w += v0 * bf16hi_to_f32(x0.w);
        b0.x += v1 * bf16lo_to_f32(x1.x);  b0.y += v1 * bf16hi_to_f32(x1.x);
        b0.z += v1 * bf16lo_to_f32(x1.y);  b0.w += v1 * bf16hi_to_f32(x1.y);
        b1.x += v1 * bf16lo_to_f32(x1.z);  b1.y += v1 * bf16hi_to_f32(x1.z);
        b1.z += v1 * bf16lo_to_f32(x1.w);  b1.w += v1 * bf16hi_to_f32(x1.w);
    }
    if (e < end) {
        const u64 p0 = __builtin_nontemporal_load(&pairs[e]);
        const int   c0 = (int)(u32)(p0 & 0xFFFFFFFFull);
        const float v0 = __uint_as_float((u32)(p0 >> 32));
        const uint4 x0 = *(const uint4*)(src + (size_t)c0 * EMB + l8 * 8);
        a0.x += v0 * bf16lo_to_f32(x0.x);  a0.y += v0 * bf16hi_to_f32(x0.x);
        a0.z += v0 * bf16lo_to_f32(x0.y);  a0.w += v0 * bf16hi_to_f32(x0.y);
        a1.x += v0 * bf16lo_to_f32(x0.z);  a1.y += v0 * bf16hi_to_f32(x0.z);
        a1.z += v0 * bf16lo_to_f32(x0.w);  a1.w += v0 * bf16hi_to_f32(x0.w);
    }
    a0.x += b0.x; a0.y += b0.y; a0.z += b0.z; a0.w += b0.w;
    a1.x += b1.x; a1.y += b1.y; a1.z += b1.z; a1.w += b1.w;

    // reduce across the 8 edge-groups (lanes differing in bits 3..5)
    #pragma unroll
    for (int m = 8; m <= 32; m <<= 1) {
        a0.x += __shfl_xor(a0.x, m); a0.y += __shfl_xor(a0.y, m);
        a0.z += __shfl_xor(a0.z, m); a0.w += __shfl_xor(a0.w, m);
        a1.x += __shfl_xor(a1.x, m); a1.y += __shfl_xor(a1.y, m);
        a1.z += __shfl_xor(a1.z, m); a1.w += __shfl_xor(a1.w, m);
    }

    if (grp == 0) {
        const size_t o = (size_t)row * EMB + l8 * 8;
        uint4 h;
        h.x = ((u32)f32_to_bf16(a0.y) << 16) | f32_to_bf16(a0.x);
        h.y = ((u32)f32_to_bf16(a0.w) << 16) | f32_to_bf16(a0.z);
        h.z = ((u32)f32_to_bf16(a1.y) << 16) | f32_to_bf16(a1.x);
        h.w = ((u32)f32_to_bf16(a1.w) << 16) | f32_to_bf16(a1.z);
        *(uint4*)(dst + o) = h;
        float4 p = *(const float4*)(acc + o);
        float4 q = *(const float4*)(acc + o + 4);
        p.x = (p.x + a0.x) * scale; p.y = (p.y + a0.y) * scale;
        p.z = (p.z + a0.z) * scale; p.w = (p.w + a0.w) * scale;
        q.x = (q.x + a1.x) * scale; q.y = (q.y + a1.y) * scale;
        q.z = (q.z + a1.z) * scale; q.w = (q.w + a1.w) * scale;
        *(float4*)(acc + o) = p;
        *(float4*)(acc + o + 4) = q;
    }
}

extern "C" void kernel_launch(void* const* d_in, const int* in_sizes, int n_in,
                              void* d_out, int out_size, void* d_ws, size_t ws_size,
                              hipStream_t stream) {
    const float* user_emb = (const float*)d_in[0];
    const float* item_emb = (const float*)d_in[1];
    const int*   adj_rows = (const int*)d_in[2];
    const int*   adj_cols = (const int*)d_in[3];
    const float* adj_vals = (const float*)d_in[4];

    float* acc = (float*)d_out;

    // workspace layout (16B-aligned chunks first)
    char* ws = (char*)d_ws;
    u16* egoA = (u16*)ws;           ws += (size_t)N_TOTAL * EMB * 2;   // 19.2 MB
    u16* egoB = (u16*)ws;           ws += (size_t)N_TOTAL * EMB * 2;   // 19.2 MB
    u64* pairs = (u64*)ws;          ws += (size_t)NNZ_CONST * 8;       // 64 MB
    int* row_ptr = (int*)ws;        ws += (size_t)(N_TOTAL + 16) * 4;
    int* cursor  = (int*)ws;        ws += (size_t)(N_TOTAL + 16) * 4;
    int* partials = (int*)ws;       ws += (size_t)256 * 4;

    const int block = 256;
    const long total4 = (long)N_TOTAL * EMB / 4;
    const int grid_elem = (int)((total4 + block - 1) / block);

    // init acc (f32) + ego0 (bf16)
    lgcn_init_kernel<<<grid_elem, block, 0, stream>>>(user_emb, item_emb, acc, egoA);

    // ---- build CSR (pairs form) ----
    (void)hipMemsetAsync(cursor, 0, (size_t)N_TOTAL * 4, stream);
    const int grid_hist = (NNZ_CONST / 4 + block - 1) / block;
    lgcn_hist_kernel<<<grid_hist, block, 0, stream>>>(adj_rows, cursor);
    lgcn_scan_reduce_kernel<<<SCAN_BLOCKS, 256, 0, stream>>>(cursor, partials);
    lgcn_scan_partials_kernel<<<1, 256, 0, stream>>>(partials, row_ptr + N_TOTAL);
    lgcn_scan_apply_kernel<<<SCAN_BLOCKS, 256, 0, stream>>>(cursor, partials,
                                                            row_ptr, cursor);
    const int grid_edge = (NNZ_CONST + block - 1) / block;
    lgcn_fill_kernel<<<grid_edge, block, 0, stream>>>(adj_rows, adj_cols, adj_vals,
                                                      cursor, pairs);

    // ---- 3 propagation layers ----
    const int grid_spmm = (N_TOTAL + 3) / 4;
    u16* src = egoA;
    u16* dst = egoB;
    for (int layer = 0; layer < 3; ++layer) {
        const float scale = (layer == 2) ? 0.25f : 1.0f;
        lgcn_spmm_kernel<<<grid_spmm, block, 0, stream>>>(
            row_ptr, pairs, src, dst, acc, scale);
        u16* t = src; src = dst; dst = t;
    }
}